// Round 1
// baseline (1453.816 us; speedup 1.0000x reference)
//
#include <hip/hip_runtime.h>
#include <float.h>

#define B  32
#define C  3
#define H  64
#define W  64
#define N  2048
#define D  128
#define KNN 8
#define PS 75   // 3*5*5 patch floats

// ---------------------------------------------------------------------------
// Kernel 1: bias[n] = 0.5 * sum(patches[n]^2)
// ---------------------------------------------------------------------------
__global__ __launch_bounds__(256) void bias_kernel(const float* __restrict__ patches,
                                                   float* __restrict__ bias) {
  int n = blockIdx.x * 256 + threadIdx.x;
  if (n < N) {
    const float* __restrict__ p = patches + n * PS;
    float s = 0.f;
#pragma unroll
    for (int j = 0; j < PS; j++) s += p[j] * p[j];
    bias[n] = 0.5f * s;
  }
}

// ---------------------------------------------------------------------------
// Kernel 2: one thread per output pixel.
//   - x-patch (75 floats) in VGPRs
//   - patches streamed via wave-uniform (scalar) loads, 2 patches/iter,
//     2 partial accumulators each -> 4 independent FMA chains
//   - streaming top-8 (register arrays, fully unrolled select/rescan)
//   - epilogue: float4 gather from values, coalesced stores
// ---------------------------------------------------------------------------
__global__ __launch_bounds__(256, 2) void topk_kernel(
    const float* __restrict__ x, const float* __restrict__ patches,
    const float* __restrict__ values, const float* __restrict__ bias,
    float* __restrict__ out) {
  const int id = blockIdx.x * 256 + threadIdx.x;
  const int w = id & 63;
  const int h = (id >> 6) & 63;
  const int b = id >> 12;

  // ---- load x-patch with zero padding (PAD=2) ----
  float xv[PS];
#pragma unroll
  for (int c = 0; c < C; c++) {
#pragma unroll
    for (int dh = 0; dh < 5; dh++) {
      const int hh = h + dh - 2;
#pragma unroll
      for (int dw = 0; dw < 5; dw++) {
        const int ww = w + dw - 2;
        const bool ok = ((unsigned)hh < 64u) && ((unsigned)ww < 64u);
        xv[(c * 5 + dh) * 5 + dw] = ok ? x[((b * C + c) * H + hh) * W + ww] : 0.f;
      }
    }
  }

  // ---- streaming top-8 state (registers) ----
  float td[KNN];
  int ti[KNN];
#pragma unroll
  for (int s = 0; s < KNN; s++) { td[s] = FLT_MAX; ti[s] = 0; }
  float tmax = FLT_MAX;
  int tslot = 0;

  for (int n = 0; n < N; n += 2) {
    const float* __restrict__ p0 = patches + n * PS;       // wave-uniform base
    const float* __restrict__ p1 = p0 + PS;
    float a0 = 0.f, a1 = 0.f, b0 = 0.f, b1 = 0.f;
#pragma unroll
    for (int j = 0; j < 38; j++) { a0 += p0[j] * xv[j]; a1 += p1[j] * xv[j]; }
#pragma unroll
    for (int j = 38; j < PS; j++) { b0 += p0[j] * xv[j]; b1 += p1[j] * xv[j]; }
    const float d0 = bias[n]     - (a0 + b0);
    const float d1 = bias[n + 1] - (a1 + b1);

    if (d0 < tmax) {                  // insert candidate n
#pragma unroll
      for (int s = 0; s < KNN; s++) if (s == tslot) { td[s] = d0; ti[s] = n; }
      float m = td[0]; int ms = 0;
#pragma unroll
      for (int s = 1; s < KNN; s++) if (td[s] > m) { m = td[s]; ms = s; }
      tmax = m; tslot = ms;
    }
    if (d1 < tmax) {                  // insert candidate n+1
#pragma unroll
      for (int s = 0; s < KNN; s++) if (s == tslot) { td[s] = d1; ti[s] = n + 1; }
      float m = td[0]; int ms = 0;
#pragma unroll
      for (int s = 1; s < KNN; s++) if (td[s] > m) { m = td[s]; ms = s; }
      tmax = m; tslot = ms;
    }
  }

  // ---- gather + mean + store ----
  const float* __restrict__ vp[KNN];
#pragma unroll
  for (int s = 0; s < KNN; s++) vp[s] = values + ti[s] * D;

  const int obase = b * (D * H * W) + h * W + w;
#pragma unroll 2
  for (int dd = 0; dd < D; dd += 4) {
    float s0 = 0.f, s1 = 0.f, s2 = 0.f, s3 = 0.f;
#pragma unroll
    for (int k = 0; k < KNN; k++) {
      const float4 v = *(const float4*)(vp[k] + dd);
      s0 += v.x; s1 += v.y; s2 += v.z; s3 += v.w;
    }
    out[obase + (dd + 0) * (H * W)] = s0 * 0.125f;
    out[obase + (dd + 1) * (H * W)] = s1 * 0.125f;
    out[obase + (dd + 2) * (H * W)] = s2 * 0.125f;
    out[obase + (dd + 3) * (H * W)] = s3 * 0.125f;
  }
}

// ---------------------------------------------------------------------------
extern "C" void kernel_launch(void* const* d_in, const int* in_sizes, int n_in,
                              void* d_out, int out_size, void* d_ws, size_t ws_size,
                              hipStream_t stream) {
  const float* x       = (const float*)d_in[0];
  const float* patches = (const float*)d_in[1];
  const float* values  = (const float*)d_in[2];
  float* out  = (float*)d_out;
  float* bias = (float*)d_ws;   // 2048 floats of scratch

  hipLaunchKernelGGL(bias_kernel, dim3(N / 256), dim3(256), 0, stream, patches, bias);
  hipLaunchKernelGGL(topk_kernel, dim3((B * H * W) / 256), dim3(256), 0, stream,
                     x, patches, values, bias, out);
}

// Round 2
// 893.864 us; speedup vs baseline: 1.6264x; 1.6264x over previous
//
#include <hip/hip_runtime.h>
#include <float.h>

#define B_  32
#define C_  3
#define H_  64
#define W_  64
#define N_  2048
#define D_  128
#define KNN 8
#define PS  75     // 3*5*5
#define NCHUNK 1024  // dictionary patches per wave (2-way split)

// ---------------------------------------------------------------------------
// Kernel 1: bias[n] = 0.5 * ||patches[n]||^2
// ---------------------------------------------------------------------------
__global__ __launch_bounds__(256) void bias_kernel(const float* __restrict__ patches,
                                                   float* __restrict__ bias) {
  int n = blockIdx.x * 256 + threadIdx.x;
  if (n < N_) {
    const float* __restrict__ p = patches + n * PS;
    float s = 0.f;
#pragma unroll
    for (int j = 0; j < PS; j++) s += p[j] * p[j];
    bias[n] = 0.5f * s;
  }
}

// streaming top-8 insert, fully unrolled, register-resident arrays
__device__ __forceinline__ void insert8(float d, int idx, float td[KNN], int ti[KNN],
                                        float& tmax, int& tslot) {
  if (d < tmax) {
#pragma unroll
    for (int s = 0; s < KNN; s++) if (s == tslot) { td[s] = d; ti[s] = idx; }
    float m = td[0]; int ms = 0;
#pragma unroll
    for (int s = 1; s < KNN; s++) if (td[s] > m) { m = td[s]; ms = s; }
    tmax = m; tslot = ms;
  }
}

// ---------------------------------------------------------------------------
// Kernel 2: block = 256 threads = 4 waves = 2 pixel-groups x 2 dictionary
// chunks. Each wave scans 1024 patches for its 64 pixels (wave-uniform patch
// base -> scalar-pipe loads). Chunk-1 waves ship their top-8 through LDS;
// chunk-0 waves merge and run the epilogue.
// amdgpu_waves_per_eu(3,4): stop the backend from spilling xv[] to chase
// 8 waves/EU the grid can never provide (round-1 failure: VGPR=56, spills).
// ---------------------------------------------------------------------------
__global__ __launch_bounds__(256)
__attribute__((amdgpu_waves_per_eu(3, 4)))
void topk_kernel(const float* __restrict__ x, const float* __restrict__ patches,
                 const float* __restrict__ values, const float* __restrict__ bias,
                 float* __restrict__ out) {
  const int lane = threadIdx.x & 63;
  const int wid = threadIdx.x >> 6;
  const int chunk = __builtin_amdgcn_readfirstlane(wid & 1);  // force uniform
  const int pgrp = wid >> 1;
  const int pix = blockIdx.x * 128 + pgrp * 64 + lane;
  const int w = pix & 63;
  const int h = (pix >> 6) & 63;
  const int b = pix >> 12;

  // ---- x-patch (75 floats) into registers, zero-padded (PAD=2) ----
  float xv[PS];
#pragma unroll
  for (int c = 0; c < C_; c++) {
#pragma unroll
    for (int dh = 0; dh < 5; dh++) {
      const int hh = h + dh - 2;
#pragma unroll
      for (int dw = 0; dw < 5; dw++) {
        const int ww = w + dw - 2;
        const bool ok = ((unsigned)hh < 64u) && ((unsigned)ww < 64u);
        xv[(c * 5 + dh) * 5 + dw] = ok ? x[((b * C_ + c) * H_ + hh) * W_ + ww] : 0.f;
      }
    }
  }

  float td[KNN];
  int ti[KNN];
#pragma unroll
  for (int s = 0; s < KNN; s++) { td[s] = FLT_MAX; ti[s] = 0; }
  float tmax = FLT_MAX;
  int tslot = 0;

  // ---- main scan: 2 patches / iter, even-odd fmaf pairs (v_pk_fma bait) ----
  const int n0 = chunk * NCHUNK;
  for (int i = 0; i < NCHUNK; i += 2) {
    const int n = n0 + i;
    const float* __restrict__ p0 = patches + n * PS;  // wave-uniform base
    const float* __restrict__ p1 = p0 + PS;
    float a0x = 0.f, a0y = 0.f, a1x = 0.f, a1y = 0.f;
    float b0x = 0.f, b0y = 0.f, b1x = 0.f, b1y = 0.f;
#pragma unroll
    for (int j = 0; j < 19; j++) {
      a0x = fmaf(p0[2 * j], xv[2 * j], a0x);
      a0y = fmaf(p0[2 * j + 1], xv[2 * j + 1], a0y);
      a1x = fmaf(p1[2 * j], xv[2 * j], a1x);
      a1y = fmaf(p1[2 * j + 1], xv[2 * j + 1], a1y);
    }
#pragma unroll
    for (int j = 19; j < 37; j++) {
      b0x = fmaf(p0[2 * j], xv[2 * j], b0x);
      b0y = fmaf(p0[2 * j + 1], xv[2 * j + 1], b0y);
      b1x = fmaf(p1[2 * j], xv[2 * j], b1x);
      b1y = fmaf(p1[2 * j + 1], xv[2 * j + 1], b1y);
    }
    b0x = fmaf(p0[74], xv[74], b0x);
    b1x = fmaf(p1[74], xv[74], b1x);
    const float d0 = bias[n] - (a0x + a0y + b0x + b0y);
    const float d1 = bias[n + 1] - (a1x + a1y + b1x + b1y);
    insert8(d0, n, td, ti, tmax, tslot);
    insert8(d1, n + 1, td, ti, tmax, tslot);
  }

  // ---- cross-wave merge through LDS ----
  __shared__ float lds_d[2][64][KNN];
  __shared__ int lds_i[2][64][KNN];
  if (chunk == 1) {
#pragma unroll
    for (int s = 0; s < KNN; s++) {
      lds_d[pgrp][lane][s] = td[s];
      lds_i[pgrp][lane][s] = ti[s];
    }
  }
  __syncthreads();
  if (chunk == 0) {
#pragma unroll
    for (int s = 0; s < KNN; s++)
      insert8(lds_d[pgrp][lane][s], lds_i[pgrp][lane][s], td, ti, tmax, tslot);

    // ---- gather + mean + store (lanes = consecutive w -> coalesced) ----
    int base[KNN];
#pragma unroll
    for (int s = 0; s < KNN; s++) base[s] = ti[s] * D_;
    const int obase = b * (D_ * H_ * W_) + h * W_ + w;
#pragma unroll 1
    for (int dd = 0; dd < D_; dd += 4) {
      float s0 = 0.f, s1 = 0.f, s2 = 0.f, s3 = 0.f;
#pragma unroll
      for (int k = 0; k < KNN; k++) {
        const float4 v = *(const float4*)(values + base[k] + dd);
        s0 += v.x; s1 += v.y; s2 += v.z; s3 += v.w;
      }
      out[obase + (dd + 0) * (H_ * W_)] = s0 * 0.125f;
      out[obase + (dd + 1) * (H_ * W_)] = s1 * 0.125f;
      out[obase + (dd + 2) * (H_ * W_)] = s2 * 0.125f;
      out[obase + (dd + 3) * (H_ * W_)] = s3 * 0.125f;
    }
  }
}

// ---------------------------------------------------------------------------
extern "C" void kernel_launch(void* const* d_in, const int* in_sizes, int n_in,
                              void* d_out, int out_size, void* d_ws, size_t ws_size,
                              hipStream_t stream) {
  const float* x = (const float*)d_in[0];
  const float* patches = (const float*)d_in[1];
  const float* values = (const float*)d_in[2];
  float* out = (float*)d_out;
  float* bias = (float*)d_ws;  // 2048 floats of scratch

  hipLaunchKernelGGL(bias_kernel, dim3(N_ / 256), dim3(256), 0, stream, patches, bias);
  hipLaunchKernelGGL(topk_kernel, dim3((B_ * H_ * W_) / 128), dim3(256), 0, stream,
                     x, patches, values, bias, out);
}